// Round 5
// baseline (261.476 us; speedup 1.0000x reference)
//
#include <hip/hip_runtime.h>

// StrokeField R11: wave-coherent early exit in the blend (T==0 compositing
// cutoff) + kD reverted to the 4-segment R9 form.
// R10 post-mortem: 8-segment kD regressed non-kF 161->190us (2x redundant
// key reads + hist atomics); kF pipeline helped only 71->67us because most
// blend iterations are DEAD WORK: expected stroke coverage depth ~70x, so
// back-to-front T hits exactly 0 after a few strokes for most chunks.
// Early exit is exact (tT==0 forever after T==0); invalid lanes init T=0
// so partial chunks also converge.

#define NC_DIM 16
#define NC (NC_DIM * NC_DIM * NC_DIM)
#define MAXS 512
#define CELL_INV 8.0f
#define CHK 128

typedef unsigned char u8;
typedef unsigned short u16;
typedef unsigned long long u64;

__device__ __forceinline__ void contract_pt(float x, float y, float z,
                                            float& cx, float& cy, float& cz) {
    float n2 = fmaf(x, x, fmaf(y, y, z * z));
    float nn = fmaxf(__builtin_amdgcn_sqrtf(n2), 1e-9f);
    float invn = 1.0f / nn;
    float scl = (nn <= 1.0f) ? 0.5f : (2.0f - invn) * (0.5f * invn);
    cx = x * scl; cy = y * scl; cz = z * scl;
}

__device__ __forceinline__ int cid_of(float cx, float cy, float cz) {
    int ix = (int)floorf((cx + 1.0f) * CELL_INV);
    int iy = (int)floorf((cy + 1.0f) * CELL_INV);
    int iz = (int)floorf((cz + 1.0f) * CELL_INV);
    ix = min(max(ix, 0), 15); iy = min(max(iy, 0), 15); iz = min(max(iz, 0), 15);
    return ix | (iy << 4) | (iz << 8);
}
__device__ __forceinline__ int sid_of(int cid) {
    return ((cid >> 2) & 3) | (((cid >> 6) & 3) << 2) | (((cid >> 10) & 3) << 4);
}
__device__ __forceinline__ int sub_of(int cid) {
    return (cid & 3) | (((cid >> 4) & 3) << 2) | (((cid >> 8) & 3) << 4);
}
__device__ __forceinline__ int cid_from(int s, int t) {
    int ix = (((s) & 3) << 2) | (t & 3);
    int iy = (((s >> 2) & 3) << 2) | ((t >> 2) & 3);
    int iz = (((s >> 4) & 3) << 2) | ((t >> 4) & 3);
    return ix | (iy << 4) | (iz << 8);
}

// KA: contract, write cw, per-block supercell count vector (no atomics).
__global__ __launch_bounds__(256) void kA(
    const float* __restrict__ coords, float* __restrict__ out,
    int* __restrict__ superCntB, int n)
{
    __shared__ int h[64];
    if (threadIdx.x < 64) h[threadIdx.x] = 0;
    __syncthreads();
    float* cw = out + 4 * (size_t)n;
    int base = blockIdx.x * 2048 + threadIdx.x;
#pragma unroll
    for (int k = 0; k < 8; ++k) {
        int i = base + k * 256;
        if (i < n) {
            float cx, cy, cz;
            contract_pt(coords[3 * i], coords[3 * i + 1], coords[3 * i + 2], cx, cy, cz);
            cw[3 * i] = cx; cw[3 * i + 1] = cy; cw[3 * i + 2] = cz;
            atomicAdd(&h[sid_of(cid_of(cx, cy, cz))], 1);
        }
    }
    __syncthreads();
    if (threadIdx.x < 64)
        superCntB[blockIdx.x * 64 + threadIdx.x] = h[threadIdx.x];
}

// KB: reduce per-block count matrix + three 64-wide shuffle scans.
__global__ __launch_bounds__(256) void kB(
    const int* __restrict__ superCntB, int nb,
    int* __restrict__ superCnt, int* __restrict__ superBase,
    int* __restrict__ superCur, int* __restrict__ superSlotBase,
    int* __restrict__ superChunkBase)
{
    __shared__ int part[4][64];
    int t = threadIdx.x, row = t >> 6, lane = t & 63;
    int acc = 0;
    for (int b = row; b < nb; b += 4) acc += superCntB[b * 64 + lane];
    part[row][lane] = acc;
    __syncthreads();
    if (t < 64) {
        int cnt = part[0][t] + part[1][t] + part[2][t] + part[3][t];
        int e = cnt;
        int sc = cnt + 64 * CHK;
        int ch = ((cnt + CHK - 1) >> 7) + 65;
        int ve = e, vs = sc, vc = ch;
        for (int off = 1; off < 64; off <<= 1) {
            int ue = __shfl_up(ve, off, 64);
            int us = __shfl_up(vs, off, 64);
            int uc = __shfl_up(vc, off, 64);
            if (t >= off) { ve += ue; vs += us; vc += uc; }
        }
        superCnt[t] = cnt;
        superBase[t] = ve - e;
        superCur[t] = ve - e;
        superSlotBase[t] = vs - sc;
        superChunkBase[t] = vc - ch;
    }
}

// KC: block-aggregated scatter of float4(cw, idx|sub<<21) + u8 key into
// supercell element runs. sortedTmp aliases out[0..4n).
__global__ __launch_bounds__(256) void kC(
    const float* __restrict__ out, int* __restrict__ superCur,
    float4* __restrict__ sortedTmp, u8* __restrict__ keyArr, int n)
{
    __shared__ int scnt[64], sbase[64];
    if (threadIdx.x < 64) scnt[threadIdx.x] = 0;
    __syncthreads();
    const float* cw = out + 4 * (size_t)n;
    int base = blockIdx.x * 2048 + threadIdx.x;
    float cx[8], cy[8], cz[8];
    int sub[8], sid[8];
#pragma unroll
    for (int k = 0; k < 8; ++k) {
        int i = base + k * 256;
        if (i < n) {
            cx[k] = cw[3 * i]; cy[k] = cw[3 * i + 1]; cz[k] = cw[3 * i + 2];
            int c = cid_of(cx[k], cy[k], cz[k]);
            sub[k] = sub_of(c); sid[k] = sid_of(c);
            atomicAdd(&scnt[sid[k]], 1);
        } else sid[k] = -1;
    }
    __syncthreads();
    if (threadIdx.x < 64) {
        int c = scnt[threadIdx.x];
        sbase[threadIdx.x] = c ? atomicAdd(&superCur[threadIdx.x], c) : 0;
        scnt[threadIdx.x] = 0;
    }
    __syncthreads();
#pragma unroll
    for (int k = 0; k < 8; ++k) {
        if (sid[k] >= 0) {
            int i = base + k * 256;
            int r = atomicAdd(&scnt[sid[k]], 1);
            int slot = sbase[sid[k]] + r;
            sortedTmp[slot] = make_float4(cx[k], cy[k], cz[k],
                                          __int_as_float(i | (sub[k] << 21)));
            keyArr[slot] = (u8)sub[k];
        }
    }
}

// KD: 4 segments per supercell (blockIdx = g*64+s, blockIdx%8==s%8 -> XCD
// pinned). Per-segment 64-bin hist from u8 keys -> deterministic cell bases
// (no global atomics); g==0 emits chunkInfo; scatter own segment into
// 128-aligned cell chunks.
__global__ __launch_bounds__(1024) void kD(
    const int* __restrict__ superCnt, const int* __restrict__ superBase,
    const int* __restrict__ superSlotBase, const int* __restrict__ superChunkBase,
    const float4* __restrict__ sortedTmp, const u8* __restrict__ keyArr,
    float4* __restrict__ sortedPts, int2* __restrict__ chunkInfo)
{
    __shared__ int hist[4][64];
    __shared__ int cur[64];
    int s = blockIdx.x & 63, g = blockIdx.x >> 6;
    int t = threadIdx.x;
    if (t < 256) ((int*)hist)[t] = 0;
    __syncthreads();
    int cnt = superCnt[s];
    int rb = superBase[s];
    int qb1 = (int)(((long long)cnt * 1) >> 2);
    int qb2 = (int)(((long long)cnt * 2) >> 2);
    int qb3 = (int)(((long long)cnt * 3) >> 2);
    for (int j = t; j < cnt; j += 1024) {
        int sub = keyArr[rb + j];
        int qr = (j >= qb2) ? ((j >= qb3) ? 3 : 2) : ((j >= qb1) ? 1 : 0);
        atomicAdd(&hist[qr][sub], 1);
    }
    __syncthreads();
    if (t < 64) {
        int c = hist[0][t] + hist[1][t] + hist[2][t] + hist[3][t];
        int slotsz = ((c + CHK - 1) >> 7) << 7;
        int nch = (c + CHK - 1) >> 7;
        int vs = slotsz, vc = nch;
        for (int off = 1; off < 64; off <<= 1) {
            int us = __shfl_up(vs, off, 64);
            int uc = __shfl_up(vc, off, 64);
            if (t >= off) { vs += us; vc += uc; }
        }
        int cellSlot = superSlotBase[s] + (vs - slotsz);
        if (g == 0) {
            int cb = superChunkBase[s] + (vc - nch);
            int cid = cid_from(s, t);
            for (int q = 0; q < nch; ++q) {
                int rem = c - (q << 7); rem = rem > CHK ? CHK : rem;
                chunkInfo[cb + q] = make_int2(cid | (rem << 16), cellSlot + (q << 7));
            }
        }
        int pre = 0;
        for (int gg = 0; gg < g; ++gg) pre += hist[gg][t];
        cur[t] = cellSlot + pre;
    }
    __syncthreads();
    int q0 = (g == 0) ? 0 : ((g == 1) ? qb1 : ((g == 2) ? qb2 : qb3));
    int q1 = (g == 0) ? qb1 : ((g == 1) ? qb2 : ((g == 2) ? qb3 : cnt));
    for (int j = q0 + t; j < q1; j += 1024) {
        float4 p = sortedTmp[rb + j];
        int bits = __float_as_int(p.w);
        int sub = (bits >> 21) & 63;
        int r = atomicAdd(&cur[sub], 1);
        p.w = __int_as_float(bits & 0x1FFFFF);
        sortedPts[r] = p;
    }
}

// KF: one wave per 128-pt chunk (2 pts/lane). On-the-fly list build, then
// 3-stage pipelined blend with wave-wide T==0 early exit.
__global__ __launch_bounds__(256) void kF(
    const float* __restrict__ shape, const float* __restrict__ color,
    const float* __restrict__ alpha,
    const int2* __restrict__ chunkInfo, const float4* __restrict__ sortedPts,
    float* __restrict__ out, int n, int ns, int maxChunks)
{
    __shared__ float4 sA[MAXS];      // (ax, ay, az, K = 0.5 - 5r)
    __shared__ float4 sB[MAXS];      // (dp, cr, cg, cb)
    __shared__ u16 wl[4][MAXS];
    for (int s = threadIdx.x; s < ns; s += blockDim.x) {
        float4 sp = ((const float4*)shape)[s];
        sA[s] = make_float4(sp.x, sp.y, sp.z, fmaf(-5.0f, sp.w, 0.5f));
        sB[s] = make_float4(fmaxf(alpha[s], 0.0f) * 50.0f,
                            color[3 * s], color[3 * s + 1], color[3 * s + 2]);
    }
    __syncthreads();

    int w = threadIdx.x >> 6, lane = threadIdx.x & 63;
    int k = blockIdx.x * 4 + w;
    if (k >= maxChunks) return;
    int2 info = chunkInfo[k];
    if (info.x < 0) return;
    int cell = info.x & 0xFFF;
    int cnum = info.x >> 16;

    float4 pA = sortedPts[info.y + lane];
    float4 pB = sortedPts[info.y + 64 + lane];
    bool vA = lane < cnum;
    bool vB = lane + 64 < cnum;
    int iA = __float_as_int(pA.w) & 0x1FFFFF;
    int iB = __float_as_int(pB.w) & 0x1FFFFF;
    float xA = pA.x, yA = pA.y, zA = pA.z;
    float xB = pB.x, yB = pB.y, zB = pB.z;

    // Build this cell's ordered stroke sublist.
    int ix = cell & 15, iy = (cell >> 4) & 15, iz = cell >> 8;
    float lox = -1.0f + ix * 0.125f, hix = lox + 0.125f;
    float loy = -1.0f + iy * 0.125f, hiy = loy + 0.125f;
    float loz = -1.0f + iz * 0.125f, hiz = loz + 0.125f;
    u16* lst = wl[w];
    int nl = 0;
    for (int bs = 0; bs < ns; bs += 64) {
        int s = bs + lane;
        bool pass = false;
        if (s < ns) {
            float4 a = sA[s];
            float dx = a.x - fminf(fmaxf(a.x, lox), hix);
            float dy = a.y - fminf(fmaxf(a.y, loy), hiy);
            float dz = a.z - fminf(fmaxf(a.z, loz), hiz);
            float d2 = fmaf(dx, dx, fmaf(dy, dy, dz * dz));
            float rr = fmaf(-0.2f, a.w, 0.201f);   // r + 0.101
            pass = d2 <= rr * rr;
        }
        u64 m = __ballot(pass);
        if (pass) lst[nl + __popcll(m & ((1ull << lane) - 1ull))] = (u16)s;
        nl += __popcll(m);
    }

    // T=0 for invalid lanes: their blends are exact no-ops and they never
    // block the wave-wide early exit.
    float TA = vA ? 1.0f : 0.0f, dA = 0.0f, rA = 0.0f, gA = 0.0f, bA = 0.0f;
    float TB = vB ? 1.0f : 0.0f, dB = 0.0f, rB = 0.0f, gB = 0.0f, bB = 0.0f;

#define BLEND(AV, BV) { \
    float dxA = xA - AV.x, dyA = yA - AV.y, dzA = zA - AV.z; \
    float d2A = fmaf(dxA, dxA, fmaf(dyA, dyA, dzA * dzA)); \
    float omtA = __builtin_amdgcn_fmed3f( \
        fmaf(5.0f, __builtin_amdgcn_sqrtf(d2A), AV.w), 0.0f, 1.0f); \
    float TnA = omtA * TA; float tTA = TA - TnA; \
    dA = fmaf(tTA, BV.x, dA); rA = fmaf(tTA, BV.y, rA); \
    gA = fmaf(tTA, BV.z, gA); bA = fmaf(tTA, BV.w, bA); TA = TnA; \
    float dxB = xB - AV.x, dyB = yB - AV.y, dzB = zB - AV.z; \
    float d2B = fmaf(dxB, dxB, fmaf(dyB, dyB, dzB * dzB)); \
    float omtB = __builtin_amdgcn_fmed3f( \
        fmaf(5.0f, __builtin_amdgcn_sqrtf(d2B), AV.w), 0.0f, 1.0f); \
    float TnB = omtB * TB; float tTB = TB - TnB; \
    dB = fmaf(tTB, BV.x, dB); rB = fmaf(tTB, BV.y, rB); \
    gB = fmaf(tTB, BV.z, gB); bB = fmaf(tTB, BV.w, bB); TB = TnB; }

#define ALL_DEAD() ((__ballot(TA != 0.0f) | __ballot(TB != 0.0f)) == 0ull)

    if (nl > 0) {
        int jb = (((nl + 63) >> 6) << 6) - 64;
        int myId = lst[min(jb + lane, nl - 1)];
        for (; jb >= 0; jb -= 64) {
            int hi = nl - jb; hi = hi > 64 ? 64 : hi;
            int nextMy = (jb >= 64) ? (int)lst[jb - 64 + lane] : 0;
            int c = hi - 1;
            int s0 = __builtin_amdgcn_readlane(myId, c);
            float4 A0 = sA[s0], B0 = sB[s0];
            int s1 = __builtin_amdgcn_readlane(myId, c >= 1 ? c - 1 : 0);
            float4 A1 = sA[s1], B1 = sB[s1];
            int s2 = __builtin_amdgcn_readlane(myId, c >= 2 ? c - 2 : 0);
            float4 A2 = sA[s2], B2 = sB[s2];
            while (c >= 3) {
                BLEND(A0, B0);
                { int sp = __builtin_amdgcn_readlane(myId, c - 3);
                  A0 = sA[sp]; B0 = sB[sp]; }
                BLEND(A1, B1);
                { int sp = __builtin_amdgcn_readlane(myId, c >= 4 ? c - 4 : 0);
                  A1 = sA[sp]; B1 = sB[sp]; }
                BLEND(A2, B2);
                { int sp = __builtin_amdgcn_readlane(myId, c >= 5 ? c - 5 : 0);
                  A2 = sA[sp]; B2 = sB[sp]; }
                c -= 3;
                if (ALL_DEAD()) goto blend_done;
            }
            if (c >= 0) BLEND(A0, B0);
            if (c >= 1) BLEND(A1, B1);
            if (c >= 2) BLEND(A2, B2);
            if (ALL_DEAD()) goto blend_done;
            myId = nextMy;
        }
    }
blend_done:
#undef BLEND
#undef ALL_DEAD

    {
        float* rgb = out + n;
        if (vA) {
            float inv = 1.0f / (1.0f + 1e-6f - TA);
            out[iA] = dA;
            rgb[3 * iA]     = fminf(fmaxf(rA * inv, 0.0f), 1.0f);
            rgb[3 * iA + 1] = fminf(fmaxf(gA * inv, 0.0f), 1.0f);
            rgb[3 * iA + 2] = fminf(fmaxf(bA * inv, 0.0f), 1.0f);
        }
        if (vB) {
            float inv = 1.0f / (1.0f + 1e-6f - TB);
            out[iB] = dB;
            rgb[3 * iB]     = fminf(fmaxf(rB * inv, 0.0f), 1.0f);
            rgb[3 * iB + 1] = fminf(fmaxf(gB * inv, 0.0f), 1.0f);
            rgb[3 * iB + 2] = fminf(fmaxf(bB * inv, 0.0f), 1.0f);
        }
    }
}

// ---- Fallback: R4 direct kernel ----
#define PTS 4
__global__ __launch_bounds__(256) void stroke_direct(
    const float* __restrict__ coords, const float* __restrict__ shape,
    const float* __restrict__ color, const float* __restrict__ alpha,
    float* __restrict__ out, int n, int ns)
{
    __shared__ float4 fA[MAXS + 1];
    __shared__ float4 fB[MAXS + 1];
    for (int s = threadIdx.x; s < ns; s += blockDim.x) {
        float4 sp = ((const float4*)shape)[s];
        fA[s + 1] = make_float4(sp.x, sp.y, sp.z, fmaf(-5.0f, sp.w, 0.5f));
        fB[s + 1] = make_float4(fmaxf(alpha[s], 0.0f) * 50.0f,
                                color[3 * s], color[3 * s + 1], color[3 * s + 2]);
    }
    __syncthreads();
    const int base = blockIdx.x * (blockDim.x * PTS) + threadIdx.x;
    float cx[PTS], cy[PTS], cz[PTS], T[PTS], Ad[PTS], Ar[PTS], Ag[PTS], Ab[PTS];
#pragma unroll
    for (int k = 0; k < PTS; ++k) {
        int i = base + k * 256; i = (i < n) ? i : (n - 1);
        contract_pt(coords[3 * i], coords[3 * i + 1], coords[3 * i + 2],
                    cx[k], cy[k], cz[k]);
        T[k] = 1.0f; Ad[k] = Ar[k] = Ag[k] = Ab[k] = 0.0f;
    }
    float4 a = fA[ns], b = fB[ns];
#pragma unroll 2
    for (int s = ns - 1; s >= 0; --s) {
        float4 an = fA[s], bn = fB[s];
#pragma unroll
        for (int k = 0; k < PTS; ++k) {
            float dx = cx[k] - a.x, dy = cy[k] - a.y, dz = cz[k] - a.z;
            float d2 = fmaf(dx, dx, fmaf(dy, dy, dz * dz));
            float dist = __builtin_amdgcn_sqrtf(d2);
            float omt = fminf(fmaxf(fmaf(5.0f, dist, a.w), 0.0f), 1.0f);
            float Tn = omt * T[k];
            float tT = T[k] - Tn;
            Ad[k] = fmaf(tT, b.x, Ad[k]); Ar[k] = fmaf(tT, b.y, Ar[k]);
            Ag[k] = fmaf(tT, b.z, Ag[k]); Ab[k] = fmaf(tT, b.w, Ab[k]);
            T[k] = Tn;
        }
        a = an; b = bn;
    }
    float* rgb = out + n;
    float* cw  = out + 4 * (size_t)n;
#pragma unroll
    for (int k = 0; k < PTS; ++k) {
        int i = base + k * 256;
        if (i >= n) break;
        float inv = 1.0f / (1.0f + 1e-6f - T[k]);
        out[i] = Ad[k];
        rgb[3 * i]     = fminf(fmaxf(Ar[k] * inv, 0.0f), 1.0f);
        rgb[3 * i + 1] = fminf(fmaxf(Ag[k] * inv, 0.0f), 1.0f);
        rgb[3 * i + 2] = fminf(fmaxf(Ab[k] * inv, 0.0f), 1.0f);
        cw[3 * i]     = cx[k];
        cw[3 * i + 1] = cy[k];
        cw[3 * i + 2] = cz[k];
    }
}

extern "C" void kernel_launch(void* const* d_in, const int* in_sizes, int n_in,
                              void* d_out, int out_size, void* d_ws, size_t ws_size,
                              hipStream_t stream) {
    const float* coords = (const float*)d_in[0];
    const float* shape  = (const float*)d_in[1];
    const float* color  = (const float*)d_in[2];
    const float* alpha  = (const float*)d_in[3];
    float* out = (float*)d_out;

    int n  = in_sizes[0] / 3;
    int ns = in_sizes[1] / 4;

    auto al = [](size_t v) { return (v + 255) & ~(size_t)255; };

    int nbA = (n + 2047) / 2048;
    int maxChunks = (n + CHK - 1) / CHK + 64 * 65;
    size_t slotCap = (size_t)n + 64 * 64 * CHK;

    size_t o_superCnt   = 0;                       // 256
    size_t o_superBase  = 256;                     // 256
    size_t o_superCur   = 512;                     // 256
    size_t o_superSlotB = 768;                     // 256
    size_t o_superChB   = 1024;                    // 256
    size_t o_superCntB  = al(1280);                // nbA*256
    size_t o_chunk      = al(o_superCntB + (size_t)nbA * 256);
    size_t o_key        = al(o_chunk + (size_t)maxChunks * 8);
    size_t o_pts        = al(o_key + (size_t)n);
    size_t need         = o_pts + slotCap * 16;

    if (ws_size >= need && ns <= MAXS && n >= 1 && n <= (1 << 21)) {
        char* w = (char*)d_ws;
        int*    superCnt  = (int*)(w + o_superCnt);
        int*    superBase = (int*)(w + o_superBase);
        int*    superCur  = (int*)(w + o_superCur);
        int*    superSlotB= (int*)(w + o_superSlotB);
        int*    superChB  = (int*)(w + o_superChB);
        int*    superCntB = (int*)(w + o_superCntB);
        int2*   chunkInfo = (int2*)(w + o_chunk);
        u8*     keyArr    = (u8*)(w + o_key);
        float4* sortedPts = (float4*)(w + o_pts);
        float4* sortedTmp = (float4*)out;          // aliases density+rgb

        hipMemsetAsync(chunkInfo, 0xFF, (size_t)maxChunks * 8, stream);

        kA<<<nbA, 256, 0, stream>>>(coords, out, superCntB, n);
        kB<<<1, 256, 0, stream>>>(superCntB, nbA, superCnt, superBase,
                                  superCur, superSlotB, superChB);
        kC<<<nbA, 256, 0, stream>>>(out, superCur, sortedTmp, keyArr, n);
        kD<<<256, 1024, 0, stream>>>(superCnt, superBase, superSlotB, superChB,
                                     sortedTmp, keyArr, sortedPts, chunkInfo);
        kF<<<(maxChunks + 3) / 4, 256, 0, stream>>>(
            shape, color, alpha, chunkInfo, sortedPts, out, n, ns, maxChunks);
    } else {
        int per_block = 256 * PTS;
        int grid = (n + per_block - 1) / per_block;
        stroke_direct<<<grid, 256, 0, stream>>>(coords, shape, color, alpha, out, n, ns);
    }
}

// Round 6
// 246.046 us; speedup vs baseline: 1.0627x; 1.0627x over previous
//
#include <hip/hip_runtime.h>

// StrokeField R12: in-place sorted-order output + gather-unsort (kG); kB fix.
// R11 post-mortem: (1) kF is WRITE-bound -- early exit cut VALU (49->37%)
// with zero time gain; 153MB amplified scatter @2.25TB/s is the clock.
// (2) R10's hidden regression was kB: one block streaming 262KB from HBM
// (~10GB/s single-CU) = ~28us; reverted to R9's 8-replica atomic scheme.
// R12: kF writes (density,rgb) IN PLACE to sortedPts[slot] (coalesced,
// L3-resident, no RMW); kD emits idxToSlot (4B scatter); new kG gathers
// (coalesced map read -> L3-hit 16B gather -> coalesced out writes).
// Scattered reads have no partial-line RMW cost; scattered writes did.

#define NC_DIM 16
#define NC (NC_DIM * NC_DIM * NC_DIM)
#define MAXS 512
#define CELL_INV 8.0f
#define CHK 128

typedef unsigned char u8;
typedef unsigned short u16;
typedef unsigned long long u64;

__device__ __forceinline__ void contract_pt(float x, float y, float z,
                                            float& cx, float& cy, float& cz) {
    float n2 = fmaf(x, x, fmaf(y, y, z * z));
    float nn = fmaxf(__builtin_amdgcn_sqrtf(n2), 1e-9f);
    float invn = 1.0f / nn;
    float scl = (nn <= 1.0f) ? 0.5f : (2.0f - invn) * (0.5f * invn);
    cx = x * scl; cy = y * scl; cz = z * scl;
}

__device__ __forceinline__ int cid_of(float cx, float cy, float cz) {
    int ix = (int)floorf((cx + 1.0f) * CELL_INV);
    int iy = (int)floorf((cy + 1.0f) * CELL_INV);
    int iz = (int)floorf((cz + 1.0f) * CELL_INV);
    ix = min(max(ix, 0), 15); iy = min(max(iy, 0), 15); iz = min(max(iz, 0), 15);
    return ix | (iy << 4) | (iz << 8);
}
__device__ __forceinline__ int sid_of(int cid) {
    return ((cid >> 2) & 3) | (((cid >> 6) & 3) << 2) | (((cid >> 10) & 3) << 4);
}
__device__ __forceinline__ int sub_of(int cid) {
    return (cid & 3) | (((cid >> 4) & 3) << 2) | (((cid >> 8) & 3) << 4);
}
__device__ __forceinline__ int cid_from(int s, int t) {
    int ix = (((s) & 3) << 2) | (t & 3);
    int iy = (((s >> 2) & 3) << 2) | ((t >> 2) & 3);
    int iz = (((s >> 4) & 3) << 2) | ((t >> 4) & 3);
    return ix | (iy << 4) | (iz << 8);
}

// KA: contract, write cw, supercell histogram (LDS-agg, 8-way replicated).
__global__ __launch_bounds__(256) void kA(
    const float* __restrict__ coords, float* __restrict__ out,
    int* __restrict__ superCntR, int n)
{
    __shared__ int h[64];
    if (threadIdx.x < 64) h[threadIdx.x] = 0;
    __syncthreads();
    float* cw = out + 4 * (size_t)n;
    int base = blockIdx.x * 2048 + threadIdx.x;
#pragma unroll
    for (int k = 0; k < 8; ++k) {
        int i = base + k * 256;
        if (i < n) {
            float cx, cy, cz;
            contract_pt(coords[3 * i], coords[3 * i + 1], coords[3 * i + 2], cx, cy, cz);
            cw[3 * i] = cx; cw[3 * i + 1] = cy; cw[3 * i + 2] = cz;
            atomicAdd(&h[sid_of(cid_of(cx, cy, cz))], 1);
        }
    }
    __syncthreads();
    if (threadIdx.x < 64 && h[threadIdx.x])
        atomicAdd(&superCntR[(blockIdx.x & 7) * 64 + threadIdx.x], h[threadIdx.x]);
}

// KB: reduce 8 replicas (2KB) + three 64-wide shuffle scans.
__global__ __launch_bounds__(64) void kB(
    const int* __restrict__ superCntR, int* __restrict__ superCnt,
    int* __restrict__ superBase, int* __restrict__ superCur,
    int* __restrict__ superSlotBase, int* __restrict__ superChunkBase)
{
    int t = threadIdx.x;
    int cnt = 0;
#pragma unroll
    for (int r = 0; r < 8; ++r) cnt += superCntR[r * 64 + t];
    int e = cnt;
    int sc = cnt + 64 * CHK;
    int ch = ((cnt + CHK - 1) >> 7) + 65;
    int ve = e, vs = sc, vc = ch;
    for (int off = 1; off < 64; off <<= 1) {
        int ue = __shfl_up(ve, off, 64);
        int us = __shfl_up(vs, off, 64);
        int uc = __shfl_up(vc, off, 64);
        if (t >= off) { ve += ue; vs += us; vc += uc; }
    }
    superCnt[t] = cnt;
    superBase[t] = ve - e;
    superCur[t] = ve - e;
    superSlotBase[t] = vs - sc;
    superChunkBase[t] = vc - ch;
}

// KC: block-aggregated scatter of float4(cw, idx|sub<<21) + u8 key into
// supercell element runs. sortedTmp aliases out[0..4n).
__global__ __launch_bounds__(256) void kC(
    const float* __restrict__ out, int* __restrict__ superCur,
    float4* __restrict__ sortedTmp, u8* __restrict__ keyArr, int n)
{
    __shared__ int scnt[64], sbase[64];
    if (threadIdx.x < 64) scnt[threadIdx.x] = 0;
    __syncthreads();
    const float* cw = out + 4 * (size_t)n;
    int base = blockIdx.x * 2048 + threadIdx.x;
    float cx[8], cy[8], cz[8];
    int sub[8], sid[8];
#pragma unroll
    for (int k = 0; k < 8; ++k) {
        int i = base + k * 256;
        if (i < n) {
            cx[k] = cw[3 * i]; cy[k] = cw[3 * i + 1]; cz[k] = cw[3 * i + 2];
            int c = cid_of(cx[k], cy[k], cz[k]);
            sub[k] = sub_of(c); sid[k] = sid_of(c);
            atomicAdd(&scnt[sid[k]], 1);
        } else sid[k] = -1;
    }
    __syncthreads();
    if (threadIdx.x < 64) {
        int c = scnt[threadIdx.x];
        sbase[threadIdx.x] = c ? atomicAdd(&superCur[threadIdx.x], c) : 0;
        scnt[threadIdx.x] = 0;
    }
    __syncthreads();
#pragma unroll
    for (int k = 0; k < 8; ++k) {
        if (sid[k] >= 0) {
            int i = base + k * 256;
            int r = atomicAdd(&scnt[sid[k]], 1);
            int slot = sbase[sid[k]] + r;
            sortedTmp[slot] = make_float4(cx[k], cy[k], cz[k],
                                          __int_as_float(i | (sub[k] << 21)));
            keyArr[slot] = (u8)sub[k];
        }
    }
}

// KD: 4 segments per supercell (blockIdx = g*64+s, XCD pinned). Per-segment
// 64-bin hist -> deterministic cell bases; g==0 emits chunkInfo; scatter own
// segment into 128-aligned cell chunks + emit idxToSlot map.
__global__ __launch_bounds__(1024) void kD(
    const int* __restrict__ superCnt, const int* __restrict__ superBase,
    const int* __restrict__ superSlotBase, const int* __restrict__ superChunkBase,
    const float4* __restrict__ sortedTmp, const u8* __restrict__ keyArr,
    float4* __restrict__ sortedPts, int* __restrict__ idxToSlot,
    int2* __restrict__ chunkInfo)
{
    __shared__ int hist[4][64];
    __shared__ int cur[64];
    int s = blockIdx.x & 63, g = blockIdx.x >> 6;
    int t = threadIdx.x;
    if (t < 256) ((int*)hist)[t] = 0;
    __syncthreads();
    int cnt = superCnt[s];
    int rb = superBase[s];
    int qb1 = (int)(((long long)cnt * 1) >> 2);
    int qb2 = (int)(((long long)cnt * 2) >> 2);
    int qb3 = (int)(((long long)cnt * 3) >> 2);
    for (int j = t; j < cnt; j += 1024) {
        int sub = keyArr[rb + j];
        int qr = (j >= qb2) ? ((j >= qb3) ? 3 : 2) : ((j >= qb1) ? 1 : 0);
        atomicAdd(&hist[qr][sub], 1);
    }
    __syncthreads();
    if (t < 64) {
        int c = hist[0][t] + hist[1][t] + hist[2][t] + hist[3][t];
        int slotsz = ((c + CHK - 1) >> 7) << 7;
        int nch = (c + CHK - 1) >> 7;
        int vs = slotsz, vc = nch;
        for (int off = 1; off < 64; off <<= 1) {
            int us = __shfl_up(vs, off, 64);
            int uc = __shfl_up(vc, off, 64);
            if (t >= off) { vs += us; vc += uc; }
        }
        int cellSlot = superSlotBase[s] + (vs - slotsz);
        if (g == 0) {
            int cb = superChunkBase[s] + (vc - nch);
            int cid = cid_from(s, t);
            for (int q = 0; q < nch; ++q) {
                int rem = c - (q << 7); rem = rem > CHK ? CHK : rem;
                chunkInfo[cb + q] = make_int2(cid | (rem << 16), cellSlot + (q << 7));
            }
        }
        int pre = 0;
        for (int gg = 0; gg < g; ++gg) pre += hist[gg][t];
        cur[t] = cellSlot + pre;
    }
    __syncthreads();
    int q0 = (g == 0) ? 0 : ((g == 1) ? qb1 : ((g == 2) ? qb2 : qb3));
    int q1 = (g == 0) ? qb1 : ((g == 1) ? qb2 : ((g == 2) ? qb3 : cnt));
    for (int j = q0 + t; j < q1; j += 1024) {
        float4 p = sortedTmp[rb + j];
        int bits = __float_as_int(p.w);
        int sub = (bits >> 21) & 63;
        int idx = bits & 0x1FFFFF;
        int r = atomicAdd(&cur[sub], 1);
        p.w = __int_as_float(idx);
        sortedPts[r] = p;
        idxToSlot[idx] = r;
    }
}

// KF: one wave per 128-pt chunk (2 pts/lane). On-the-fly list build, 3-stage
// pipelined blend with wave-wide T==0 early exit, IN-PLACE result write:
// sortedPts[slot] <- (density, r, g, b). No scattered output.
__global__ __launch_bounds__(256) void kF(
    const float* __restrict__ shape, const float* __restrict__ color,
    const float* __restrict__ alpha,
    const int2* __restrict__ chunkInfo, float4* __restrict__ sortedPts,
    int ns, int maxChunks)
{
    __shared__ float4 sA[MAXS];      // (ax, ay, az, K = 0.5 - 5r)
    __shared__ float4 sB[MAXS];      // (dp, cr, cg, cb)
    __shared__ u16 wl[4][MAXS];
    for (int s = threadIdx.x; s < ns; s += blockDim.x) {
        float4 sp = ((const float4*)shape)[s];
        sA[s] = make_float4(sp.x, sp.y, sp.z, fmaf(-5.0f, sp.w, 0.5f));
        sB[s] = make_float4(fmaxf(alpha[s], 0.0f) * 50.0f,
                            color[3 * s], color[3 * s + 1], color[3 * s + 2]);
    }
    __syncthreads();

    int w = threadIdx.x >> 6, lane = threadIdx.x & 63;
    int k = blockIdx.x * 4 + w;
    if (k >= maxChunks) return;
    int2 info = chunkInfo[k];
    if (info.x < 0) return;
    int cnum = info.x >> 16;
    int cell = info.x & 0xFFF;

    float4 pA = sortedPts[info.y + lane];
    float4 pB = sortedPts[info.y + 64 + lane];
    bool vA = lane < cnum;
    bool vB = lane + 64 < cnum;
    // keep pad-lane coords finite (pad slots hold stale data; NaN would
    // poison T and defeat the wave-wide early exit)
    float xA = vA ? pA.x : 1e9f, yA = vA ? pA.y : 1e9f, zA = vA ? pA.z : 1e9f;
    float xB = vB ? pB.x : 1e9f, yB = vB ? pB.y : 1e9f, zB = vB ? pB.z : 1e9f;

    // Build this cell's ordered stroke sublist.
    int ix = cell & 15, iy = (cell >> 4) & 15, iz = cell >> 8;
    float lox = -1.0f + ix * 0.125f, hix = lox + 0.125f;
    float loy = -1.0f + iy * 0.125f, hiy = loy + 0.125f;
    float loz = -1.0f + iz * 0.125f, hiz = loz + 0.125f;
    u16* lst = wl[w];
    int nl = 0;
    for (int bs = 0; bs < ns; bs += 64) {
        int s = bs + lane;
        bool pass = false;
        if (s < ns) {
            float4 a = sA[s];
            float dx = a.x - fminf(fmaxf(a.x, lox), hix);
            float dy = a.y - fminf(fmaxf(a.y, loy), hiy);
            float dz = a.z - fminf(fmaxf(a.z, loz), hiz);
            float d2 = fmaf(dx, dx, fmaf(dy, dy, dz * dz));
            float rr = fmaf(-0.2f, a.w, 0.201f);   // r + 0.101
            pass = d2 <= rr * rr;
        }
        u64 m = __ballot(pass);
        if (pass) lst[nl + __popcll(m & ((1ull << lane) - 1ull))] = (u16)s;
        nl += __popcll(m);
    }

    float TA = vA ? 1.0f : 0.0f, dA = 0.0f, rA = 0.0f, gA = 0.0f, bA = 0.0f;
    float TB = vB ? 1.0f : 0.0f, dB = 0.0f, rB = 0.0f, gB = 0.0f, bB = 0.0f;

#define BLEND(AV, BV) { \
    float dxA = xA - AV.x, dyA = yA - AV.y, dzA = zA - AV.z; \
    float d2A = fmaf(dxA, dxA, fmaf(dyA, dyA, dzA * dzA)); \
    float omtA = __builtin_amdgcn_fmed3f( \
        fmaf(5.0f, __builtin_amdgcn_sqrtf(d2A), AV.w), 0.0f, 1.0f); \
    float TnA = omtA * TA; float tTA = TA - TnA; \
    dA = fmaf(tTA, BV.x, dA); rA = fmaf(tTA, BV.y, rA); \
    gA = fmaf(tTA, BV.z, gA); bA = fmaf(tTA, BV.w, bA); TA = TnA; \
    float dxB = xB - AV.x, dyB = yB - AV.y, dzB = zB - AV.z; \
    float d2B = fmaf(dxB, dxB, fmaf(dyB, dyB, dzB * dzB)); \
    float omtB = __builtin_amdgcn_fmed3f( \
        fmaf(5.0f, __builtin_amdgcn_sqrtf(d2B), AV.w), 0.0f, 1.0f); \
    float TnB = omtB * TB; float tTB = TB - TnB; \
    dB = fmaf(tTB, BV.x, dB); rB = fmaf(tTB, BV.y, rB); \
    gB = fmaf(tTB, BV.z, gB); bB = fmaf(tTB, BV.w, bB); TB = TnB; }

#define ALL_DEAD() ((__ballot(TA != 0.0f) | __ballot(TB != 0.0f)) == 0ull)

    if (nl > 0) {
        int jb = (((nl + 63) >> 6) << 6) - 64;
        int myId = lst[min(jb + lane, nl - 1)];
        for (; jb >= 0; jb -= 64) {
            int hi = nl - jb; hi = hi > 64 ? 64 : hi;
            int nextMy = (jb >= 64) ? (int)lst[jb - 64 + lane] : 0;
            int c = hi - 1;
            int s0 = __builtin_amdgcn_readlane(myId, c);
            float4 A0 = sA[s0], B0 = sB[s0];
            int s1 = __builtin_amdgcn_readlane(myId, c >= 1 ? c - 1 : 0);
            float4 A1 = sA[s1], B1 = sB[s1];
            int s2 = __builtin_amdgcn_readlane(myId, c >= 2 ? c - 2 : 0);
            float4 A2 = sA[s2], B2 = sB[s2];
            while (c >= 3) {
                BLEND(A0, B0);
                { int sp = __builtin_amdgcn_readlane(myId, c - 3);
                  A0 = sA[sp]; B0 = sB[sp]; }
                BLEND(A1, B1);
                { int sp = __builtin_amdgcn_readlane(myId, c >= 4 ? c - 4 : 0);
                  A1 = sA[sp]; B1 = sB[sp]; }
                BLEND(A2, B2);
                { int sp = __builtin_amdgcn_readlane(myId, c >= 5 ? c - 5 : 0);
                  A2 = sA[sp]; B2 = sB[sp]; }
                c -= 3;
                if (ALL_DEAD()) goto blend_done;
            }
            if (c >= 0) BLEND(A0, B0);
            if (c >= 1) BLEND(A1, B1);
            if (c >= 2) BLEND(A2, B2);
            if (ALL_DEAD()) goto blend_done;
            myId = nextMy;
        }
    }
blend_done:
#undef BLEND
#undef ALL_DEAD

    {
        // In-place coalesced result write (post-normalized). Pad lanes write
        // zeros to pad slots -- never referenced by idxToSlot.
        float invA = 1.0f / (1.0f + 1e-6f - TA);
        sortedPts[info.y + lane] = make_float4(
            dA,
            fminf(fmaxf(rA * invA, 0.0f), 1.0f),
            fminf(fmaxf(gA * invA, 0.0f), 1.0f),
            fminf(fmaxf(bA * invA, 0.0f), 1.0f));
        float invB = 1.0f / (1.0f + 1e-6f - TB);
        sortedPts[info.y + 64 + lane] = make_float4(
            dB,
            fminf(fmaxf(rB * invB, 0.0f), 1.0f),
            fminf(fmaxf(gB * invB, 0.0f), 1.0f),
            fminf(fmaxf(bB * invB, 0.0f), 1.0f));
    }
}

// KG: gather-unsort. Coalesced idxToSlot read -> L3-hit 16B gather ->
// fully coalesced density+rgb writes.
__global__ __launch_bounds__(256) void kG(
    const int* __restrict__ idxToSlot, const float4* __restrict__ sortedPts,
    float* __restrict__ out, int n)
{
    float* rgb = out + n;
    int base = blockIdx.x * 2048 + threadIdx.x;
#pragma unroll
    for (int k = 0; k < 8; ++k) {
        int i = base + k * 256;
        if (i < n) {
            float4 v = sortedPts[idxToSlot[i]];
            out[i] = v.x;
            rgb[3 * i]     = v.y;
            rgb[3 * i + 1] = v.z;
            rgb[3 * i + 2] = v.w;
        }
    }
}

// ---- Fallback: R4 direct kernel ----
#define PTS 4
__global__ __launch_bounds__(256) void stroke_direct(
    const float* __restrict__ coords, const float* __restrict__ shape,
    const float* __restrict__ color, const float* __restrict__ alpha,
    float* __restrict__ out, int n, int ns)
{
    __shared__ float4 fA[MAXS + 1];
    __shared__ float4 fB[MAXS + 1];
    for (int s = threadIdx.x; s < ns; s += blockDim.x) {
        float4 sp = ((const float4*)shape)[s];
        fA[s + 1] = make_float4(sp.x, sp.y, sp.z, fmaf(-5.0f, sp.w, 0.5f));
        fB[s + 1] = make_float4(fmaxf(alpha[s], 0.0f) * 50.0f,
                                color[3 * s], color[3 * s + 1], color[3 * s + 2]);
    }
    __syncthreads();
    const int base = blockIdx.x * (blockDim.x * PTS) + threadIdx.x;
    float cx[PTS], cy[PTS], cz[PTS], T[PTS], Ad[PTS], Ar[PTS], Ag[PTS], Ab[PTS];
#pragma unroll
    for (int k = 0; k < PTS; ++k) {
        int i = base + k * 256; i = (i < n) ? i : (n - 1);
        contract_pt(coords[3 * i], coords[3 * i + 1], coords[3 * i + 2],
                    cx[k], cy[k], cz[k]);
        T[k] = 1.0f; Ad[k] = Ar[k] = Ag[k] = Ab[k] = 0.0f;
    }
    float4 a = fA[ns], b = fB[ns];
#pragma unroll 2
    for (int s = ns - 1; s >= 0; --s) {
        float4 an = fA[s], bn = fB[s];
#pragma unroll
        for (int k = 0; k < PTS; ++k) {
            float dx = cx[k] - a.x, dy = cy[k] - a.y, dz = cz[k] - a.z;
            float d2 = fmaf(dx, dx, fmaf(dy, dy, dz * dz));
            float dist = __builtin_amdgcn_sqrtf(d2);
            float omt = fminf(fmaxf(fmaf(5.0f, dist, a.w), 0.0f), 1.0f);
            float Tn = omt * T[k];
            float tT = T[k] - Tn;
            Ad[k] = fmaf(tT, b.x, Ad[k]); Ar[k] = fmaf(tT, b.y, Ar[k]);
            Ag[k] = fmaf(tT, b.z, Ag[k]); Ab[k] = fmaf(tT, b.w, Ab[k]);
            T[k] = Tn;
        }
        a = an; b = bn;
    }
    float* rgb = out + n;
    float* cw  = out + 4 * (size_t)n;
#pragma unroll
    for (int k = 0; k < PTS; ++k) {
        int i = base + k * 256;
        if (i >= n) break;
        float inv = 1.0f / (1.0f + 1e-6f - T[k]);
        out[i] = Ad[k];
        rgb[3 * i]     = fminf(fmaxf(Ar[k] * inv, 0.0f), 1.0f);
        rgb[3 * i + 1] = fminf(fmaxf(Ag[k] * inv, 0.0f), 1.0f);
        rgb[3 * i + 2] = fminf(fmaxf(Ab[k] * inv, 0.0f), 1.0f);
        cw[3 * i]     = cx[k];
        cw[3 * i + 1] = cy[k];
        cw[3 * i + 2] = cz[k];
    }
}

extern "C" void kernel_launch(void* const* d_in, const int* in_sizes, int n_in,
                              void* d_out, int out_size, void* d_ws, size_t ws_size,
                              hipStream_t stream) {
    const float* coords = (const float*)d_in[0];
    const float* shape  = (const float*)d_in[1];
    const float* color  = (const float*)d_in[2];
    const float* alpha  = (const float*)d_in[3];
    float* out = (float*)d_out;

    int n  = in_sizes[0] / 3;
    int ns = in_sizes[1] / 4;

    auto al = [](size_t v) { return (v + 255) & ~(size_t)255; };

    int nbA = (n + 2047) / 2048;
    int maxChunks = (n + CHK - 1) / CHK + 64 * 65;
    size_t slotCap = (size_t)n + 64 * 64 * CHK;

    size_t o_superCntR  = 0;                       // 2048
    size_t o_superCnt   = 2048;                    // 256
    size_t o_superBase  = 2304;                    // 256
    size_t o_superCur   = 2560;                    // 256
    size_t o_superSlotB = 2816;                    // 256
    size_t o_superChB   = 3072;                    // 256
    size_t o_chunk      = al(3328);                // maxChunks*8
    size_t o_key        = al(o_chunk + (size_t)maxChunks * 8);   // n
    size_t o_i2s        = al(o_key + (size_t)n);                 // n*4
    size_t o_pts        = al(o_i2s + (size_t)n * 4);             // slotCap*16
    size_t need         = o_pts + slotCap * 16;

    if (ws_size >= need && ns <= MAXS && n >= 1 && n <= (1 << 21)) {
        char* w = (char*)d_ws;
        int*    superCntR = (int*)(w + o_superCntR);
        int*    superCnt  = (int*)(w + o_superCnt);
        int*    superBase = (int*)(w + o_superBase);
        int*    superCur  = (int*)(w + o_superCur);
        int*    superSlotB= (int*)(w + o_superSlotB);
        int*    superChB  = (int*)(w + o_superChB);
        int2*   chunkInfo = (int2*)(w + o_chunk);
        u8*     keyArr    = (u8*)(w + o_key);
        int*    idxToSlot = (int*)(w + o_i2s);
        float4* sortedPts = (float4*)(w + o_pts);
        float4* sortedTmp = (float4*)out;          // aliases density+rgb

        hipMemsetAsync(superCntR, 0, 2048, stream);
        hipMemsetAsync(chunkInfo, 0xFF, (size_t)maxChunks * 8, stream);

        kA<<<nbA, 256, 0, stream>>>(coords, out, superCntR, n);
        kB<<<1, 64, 0, stream>>>(superCntR, superCnt, superBase, superCur,
                                 superSlotB, superChB);
        kC<<<nbA, 256, 0, stream>>>(out, superCur, sortedTmp, keyArr, n);
        kD<<<256, 1024, 0, stream>>>(superCnt, superBase, superSlotB, superChB,
                                     sortedTmp, keyArr, sortedPts, idxToSlot,
                                     chunkInfo);
        kF<<<(maxChunks + 3) / 4, 256, 0, stream>>>(
            shape, color, alpha, chunkInfo, sortedPts, ns, maxChunks);
        kG<<<nbA, 256, 0, stream>>>(idxToSlot, sortedPts, out, n);
    } else {
        int per_block = 256 * PTS;
        int grid = (n + per_block - 1) / per_block;
        stroke_direct<<<grid, 256, 0, stream>>>(coords, shape, color, alpha, out, n, ns);
    }
}

// Round 7
// 240.017 us; speedup vs baseline: 1.0894x; 1.0251x over previous
//
#include <hip/hip_runtime.h>

// StrokeField R13: coalesced two-hop unsort map + factored histogram + fused
// reverse-order test/blend in kF.
// R12 post-mortem: kD became top kernel (57us, occ 19%, VALU 4.6%, WRITE
// 93MB): (a) idxToSlot was a device-wide 4B scatter (same partial-line RMW
// disease R12 cured in kF); (b) each of 4 blocks/supercell re-read ALL keys
// for the hist (4x redundant), 256 blocks badly balanced. Also exonerates
// R10's 8-seg kD -- the R10 regression was kB.
// R13: kC writes idxToRun[i] (coalesced); kD writes runToSlot[rb+j]
// (coalesced); kG does i->run->slot gathers (L3-resident reads, no RMW).
// kH (1024 blk) hists each key once; kB2 (64 blk) scans + chunkInfo incl.
// tails (memset dies); kD = pure scatter, 16 seg/supercell, XCD-pinned.
// kF: 64-stroke blocks from the END: test+compact, blend descending,
// wave-dead check skips BOTH test and blend of remaining strokes.

#define NC_DIM 16
#define NC (NC_DIM * NC_DIM * NC_DIM)
#define MAXS 512
#define CELL_INV 8.0f
#define CHK 128
#define NSEG 16

typedef unsigned char u8;
typedef unsigned short u16;
typedef unsigned long long u64;

__device__ __forceinline__ void contract_pt(float x, float y, float z,
                                            float& cx, float& cy, float& cz) {
    float n2 = fmaf(x, x, fmaf(y, y, z * z));
    float nn = fmaxf(__builtin_amdgcn_sqrtf(n2), 1e-9f);
    float invn = 1.0f / nn;
    float scl = (nn <= 1.0f) ? 0.5f : (2.0f - invn) * (0.5f * invn);
    cx = x * scl; cy = y * scl; cz = z * scl;
}

__device__ __forceinline__ int cid_of(float cx, float cy, float cz) {
    int ix = (int)floorf((cx + 1.0f) * CELL_INV);
    int iy = (int)floorf((cy + 1.0f) * CELL_INV);
    int iz = (int)floorf((cz + 1.0f) * CELL_INV);
    ix = min(max(ix, 0), 15); iy = min(max(iy, 0), 15); iz = min(max(iz, 0), 15);
    return ix | (iy << 4) | (iz << 8);
}
__device__ __forceinline__ int sid_of(int cid) {
    return ((cid >> 2) & 3) | (((cid >> 6) & 3) << 2) | (((cid >> 10) & 3) << 4);
}
__device__ __forceinline__ int sub_of(int cid) {
    return (cid & 3) | (((cid >> 4) & 3) << 2) | (((cid >> 8) & 3) << 4);
}
__device__ __forceinline__ int cid_from(int s, int t) {
    int ix = (((s) & 3) << 2) | (t & 3);
    int iy = (((s >> 2) & 3) << 2) | ((t >> 2) & 3);
    int iz = (((s >> 4) & 3) << 2) | ((t >> 4) & 3);
    return ix | (iy << 4) | (iz << 8);
}

// KA: contract, write cw, supercell histogram (LDS-agg, 8-way replicated).
__global__ __launch_bounds__(256) void kA(
    const float* __restrict__ coords, float* __restrict__ out,
    int* __restrict__ superCntR, int n)
{
    __shared__ int h[64];
    if (threadIdx.x < 64) h[threadIdx.x] = 0;
    __syncthreads();
    float* cw = out + 4 * (size_t)n;
    int base = blockIdx.x * 2048 + threadIdx.x;
#pragma unroll
    for (int k = 0; k < 8; ++k) {
        int i = base + k * 256;
        if (i < n) {
            float cx, cy, cz;
            contract_pt(coords[3 * i], coords[3 * i + 1], coords[3 * i + 2], cx, cy, cz);
            cw[3 * i] = cx; cw[3 * i + 1] = cy; cw[3 * i + 2] = cz;
            atomicAdd(&h[sid_of(cid_of(cx, cy, cz))], 1);
        }
    }
    __syncthreads();
    if (threadIdx.x < 64 && h[threadIdx.x])
        atomicAdd(&superCntR[(blockIdx.x & 7) * 64 + threadIdx.x], h[threadIdx.x]);
}

// KB: reduce 8 replicas (2KB) + three 64-wide shuffle scans.
__global__ __launch_bounds__(64) void kB(
    const int* __restrict__ superCntR, int* __restrict__ superCnt,
    int* __restrict__ superBase, int* __restrict__ superCur,
    int* __restrict__ superSlotBase, int* __restrict__ superChunkBase)
{
    int t = threadIdx.x;
    int cnt = 0;
#pragma unroll
    for (int r = 0; r < 8; ++r) cnt += superCntR[r * 64 + t];
    int e = cnt;
    int sc = cnt + 64 * CHK;
    int ch = ((cnt + CHK - 1) >> 7) + 65;
    int ve = e, vs = sc, vc = ch;
    for (int off = 1; off < 64; off <<= 1) {
        int ue = __shfl_up(ve, off, 64);
        int us = __shfl_up(vs, off, 64);
        int uc = __shfl_up(vc, off, 64);
        if (t >= off) { ve += ue; vs += us; vc += uc; }
    }
    superCnt[t] = cnt;
    superBase[t] = ve - e;
    superCur[t] = ve - e;
    superSlotBase[t] = vs - sc;
    superChunkBase[t] = vc - ch;
}

// KC: block-aggregated scatter of float4(cw, idx|sub<<21) + u8 key into
// supercell runs; idxToRun[i] written COALESCED. sortedTmp aliases out[0..4n).
__global__ __launch_bounds__(256) void kC(
    const float* __restrict__ out, int* __restrict__ superCur,
    float4* __restrict__ sortedTmp, u8* __restrict__ keyArr,
    int* __restrict__ idxToRun, int n)
{
    __shared__ int scnt[64], sbase[64];
    if (threadIdx.x < 64) scnt[threadIdx.x] = 0;
    __syncthreads();
    const float* cw = out + 4 * (size_t)n;
    int base = blockIdx.x * 2048 + threadIdx.x;
    float cx[8], cy[8], cz[8];
    int sub[8], sid[8];
#pragma unroll
    for (int k = 0; k < 8; ++k) {
        int i = base + k * 256;
        if (i < n) {
            cx[k] = cw[3 * i]; cy[k] = cw[3 * i + 1]; cz[k] = cw[3 * i + 2];
            int c = cid_of(cx[k], cy[k], cz[k]);
            sub[k] = sub_of(c); sid[k] = sid_of(c);
            atomicAdd(&scnt[sid[k]], 1);
        } else sid[k] = -1;
    }
    __syncthreads();
    if (threadIdx.x < 64) {
        int c = scnt[threadIdx.x];
        sbase[threadIdx.x] = c ? atomicAdd(&superCur[threadIdx.x], c) : 0;
        scnt[threadIdx.x] = 0;
    }
    __syncthreads();
#pragma unroll
    for (int k = 0; k < 8; ++k) {
        if (sid[k] >= 0) {
            int i = base + k * 256;
            int r = atomicAdd(&scnt[sid[k]], 1);
            int run = sbase[sid[k]] + r;
            sortedTmp[run] = make_float4(cx[k], cy[k], cz[k],
                                         __int_as_float(i | (sub[k] << 21)));
            keyArr[run] = (u8)sub[k];
            idxToRun[i] = run;
        }
    }
}

// KH: per-(supercell, 1/16-segment) 64-bin histogram; each key read ONCE.
__global__ __launch_bounds__(256) void kH(
    const int* __restrict__ superCnt, const int* __restrict__ superBase,
    const u8* __restrict__ keyArr, int* __restrict__ segHist)
{
    __shared__ int h[64];
    int s = blockIdx.x & 63, seg = blockIdx.x >> 6;
    if (threadIdx.x < 64) h[threadIdx.x] = 0;
    __syncthreads();
    int cnt = superCnt[s], rb = superBase[s];
    int j0 = (int)(((long long)cnt * seg) >> 4);
    int j1 = (int)(((long long)cnt * (seg + 1)) >> 4);
    for (int j = j0 + threadIdx.x; j < j1; j += 256)
        atomicAdd(&h[keyArr[rb + j]], 1);
    __syncthreads();
    if (threadIdx.x < 64)
        segHist[(s * NSEG + seg) * 64 + threadIdx.x] = h[threadIdx.x];
}

// KB2: one block per supercell. Chunk/slot scans over 64 cells, chunkInfo
// (incl. -1 tails -> no memset), per-(cell,seg) starting cursors.
__global__ __launch_bounds__(64) void kB2(
    const int* __restrict__ superCnt, const int* __restrict__ superSlotBase,
    const int* __restrict__ superChunkBase, const int* __restrict__ segHist,
    int* __restrict__ cellSegCur, int2* __restrict__ chunkInfo, int maxChunks)
{
    int s = blockIdx.x, t = threadIdx.x;   // t = cell (sub) index
    int segc[NSEG];
    int c = 0;
#pragma unroll
    for (int g = 0; g < NSEG; ++g) {
        segc[g] = segHist[(s * NSEG + g) * 64 + t];
        c += segc[g];
    }
    int nch = (c + CHK - 1) >> 7;
    int slotsz = nch << 7;
    int vs = slotsz, vc = nch;
    for (int off = 1; off < 64; off <<= 1) {
        int us = __shfl_up(vs, off, 64);
        int uc = __shfl_up(vc, off, 64);
        if (t >= off) { vs += us; vc += uc; }
    }
    int cellSlot = superSlotBase[s] + (vs - slotsz);
    int cb0 = superChunkBase[s];
    int cb = cb0 + (vc - nch);
    int cid = cid_from(s, t);
    for (int q = 0; q < nch; ++q) {
        int rem = c - (q << 7); rem = rem > CHK ? CHK : rem;
        chunkInfo[cb + q] = make_int2(cid | (rem << 16), cellSlot + (q << 7));
    }
    int used = __shfl(vc, 63, 64);
    int cnt = superCnt[s];
    int cap = ((cnt + CHK - 1) >> 7) + 65;
    if (s == 63) cap = maxChunks - cb0;
    for (int q = used + t; q < cap; q += 64)
        chunkInfo[cb0 + q] = make_int2(-1, 0);
    int run = cellSlot;
#pragma unroll
    for (int g = 0; g < NSEG; ++g) {
        cellSegCur[(s * NSEG + g) * 64 + t] = run;
        run += segc[g];
    }
}

// KD: pure forwarding scatter. 16 segments/supercell (blockIdx = seg*64+s,
// blockIdx%8==s%8 -> XCD pinned). runToSlot written COALESCED in j.
__global__ __launch_bounds__(256) void kD(
    const int* __restrict__ superCnt, const int* __restrict__ superBase,
    const int* __restrict__ cellSegCur, const float4* __restrict__ sortedTmp,
    float4* __restrict__ sortedPts, int* __restrict__ runToSlot)
{
    __shared__ int cur[64];
    int s = blockIdx.x & 63, seg = blockIdx.x >> 6;
    int t = threadIdx.x;
    if (t < 64) cur[t] = cellSegCur[(s * NSEG + seg) * 64 + t];
    __syncthreads();
    int cnt = superCnt[s], rb = superBase[s];
    int j0 = (int)(((long long)cnt * seg) >> 4);
    int j1 = (int)(((long long)cnt * (seg + 1)) >> 4);
    for (int j = j0 + t; j < j1; j += 256) {
        float4 p = sortedTmp[rb + j];
        int bits = __float_as_int(p.w);
        int sub = (bits >> 21) & 63;
        int r = atomicAdd(&cur[sub], 1);
        p.w = __int_as_float(bits & 0x1FFFFF);
        sortedPts[r] = p;
        runToSlot[rb + j] = r;
    }
}

// KF: one wave per 128-pt chunk (2 pts/lane). FUSED reverse-order stroke
// test + blend: per 64-stroke block (from the END), ballot-compact the
// passing strokes, blend them descending (3-stage readlane pipeline),
// wave-dead check skips both test and blend of all earlier strokes.
// Results written IN PLACE to sortedPts (coalesced).
__global__ __launch_bounds__(256) void kF(
    const float* __restrict__ shape, const float* __restrict__ color,
    const float* __restrict__ alpha,
    const int2* __restrict__ chunkInfo, float4* __restrict__ sortedPts,
    int ns, int maxChunks)
{
    __shared__ float4 sA[MAXS];      // (ax, ay, az, K = 0.5 - 5r)
    __shared__ float4 sB[MAXS];      // (dp, cr, cg, cb)
    __shared__ u16 wl[4][64];
    for (int s = threadIdx.x; s < ns; s += blockDim.x) {
        float4 sp = ((const float4*)shape)[s];
        sA[s] = make_float4(sp.x, sp.y, sp.z, fmaf(-5.0f, sp.w, 0.5f));
        sB[s] = make_float4(fmaxf(alpha[s], 0.0f) * 50.0f,
                            color[3 * s], color[3 * s + 1], color[3 * s + 2]);
    }
    __syncthreads();

    int w = threadIdx.x >> 6, lane = threadIdx.x & 63;
    int k = blockIdx.x * 4 + w;
    if (k >= maxChunks) return;
    int2 info = chunkInfo[k];
    if (info.x < 0) return;
    int cnum = info.x >> 16;
    int cell = info.x & 0xFFF;

    float4 pA = sortedPts[info.y + lane];
    float4 pB = sortedPts[info.y + 64 + lane];
    bool vA = lane < cnum;
    bool vB = lane + 64 < cnum;
    float xA = vA ? pA.x : 1e9f, yA = vA ? pA.y : 1e9f, zA = vA ? pA.z : 1e9f;
    float xB = vB ? pB.x : 1e9f, yB = vB ? pB.y : 1e9f, zB = vB ? pB.z : 1e9f;

    int ix = cell & 15, iy = (cell >> 4) & 15, iz = cell >> 8;
    float lox = -1.0f + ix * 0.125f, hix = lox + 0.125f;
    float loy = -1.0f + iy * 0.125f, hiy = loy + 0.125f;
    float loz = -1.0f + iz * 0.125f, hiz = loz + 0.125f;
    u16* lst = wl[w];

    float TA = vA ? 1.0f : 0.0f, dA = 0.0f, rA = 0.0f, gA = 0.0f, bA = 0.0f;
    float TB = vB ? 1.0f : 0.0f, dB = 0.0f, rB = 0.0f, gB = 0.0f, bB = 0.0f;

#define BLEND(AV, BV) { \
    float dxA = xA - AV.x, dyA = yA - AV.y, dzA = zA - AV.z; \
    float d2A = fmaf(dxA, dxA, fmaf(dyA, dyA, dzA * dzA)); \
    float omtA = __builtin_amdgcn_fmed3f( \
        fmaf(5.0f, __builtin_amdgcn_sqrtf(d2A), AV.w), 0.0f, 1.0f); \
    float TnA = omtA * TA; float tTA = TA - TnA; \
    dA = fmaf(tTA, BV.x, dA); rA = fmaf(tTA, BV.y, rA); \
    gA = fmaf(tTA, BV.z, gA); bA = fmaf(tTA, BV.w, bA); TA = TnA; \
    float dxB = xB - AV.x, dyB = yB - AV.y, dzB = zB - AV.z; \
    float d2B = fmaf(dxB, dxB, fmaf(dyB, dyB, dzB * dzB)); \
    float omtB = __builtin_amdgcn_fmed3f( \
        fmaf(5.0f, __builtin_amdgcn_sqrtf(d2B), AV.w), 0.0f, 1.0f); \
    float TnB = omtB * TB; float tTB = TB - TnB; \
    dB = fmaf(tTB, BV.x, dB); rB = fmaf(tTB, BV.y, rB); \
    gB = fmaf(tTB, BV.z, gB); bB = fmaf(tTB, BV.w, bB); TB = TnB; }

#define ALL_DEAD() ((__ballot(TA != 0.0f) | __ballot(TB != 0.0f)) == 0ull)

    // Stroke blocks from the END (descending composite order preserved).
    for (int bs = ((((ns + 63) >> 6) << 6)) - 64; bs >= 0; bs -= 64) {
        int s = bs + lane;
        bool pass = false;
        if (s < ns) {
            float4 a = sA[s];
            float dx = a.x - fminf(fmaxf(a.x, lox), hix);
            float dy = a.y - fminf(fmaxf(a.y, loy), hiy);
            float dz = a.z - fminf(fmaxf(a.z, loz), hiz);
            float d2 = fmaf(dx, dx, fmaf(dy, dy, dz * dz));
            float rr = fmaf(-0.2f, a.w, 0.201f);   // r + 0.101
            pass = d2 <= rr * rr;
        }
        u64 m = __ballot(pass);
        int cnt = __popcll(m);
        if (!cnt) continue;
        if (pass) lst[__popcll(m & ((1ull << lane) - 1ull))] = (u16)s;
        int myId = lst[lane];            // same-wave LDS, in-order
        int c = cnt - 1;
        int s0 = __builtin_amdgcn_readlane(myId, c);
        float4 A0 = sA[s0], B0 = sB[s0];
        int s1 = __builtin_amdgcn_readlane(myId, c >= 1 ? c - 1 : 0);
        float4 A1 = sA[s1], B1 = sB[s1];
        int s2 = __builtin_amdgcn_readlane(myId, c >= 2 ? c - 2 : 0);
        float4 A2 = sA[s2], B2 = sB[s2];
        while (c >= 3) {
            BLEND(A0, B0);
            { int sp = __builtin_amdgcn_readlane(myId, c - 3);
              A0 = sA[sp]; B0 = sB[sp]; }
            BLEND(A1, B1);
            { int sp = __builtin_amdgcn_readlane(myId, c >= 4 ? c - 4 : 0);
              A1 = sA[sp]; B1 = sB[sp]; }
            BLEND(A2, B2);
            { int sp = __builtin_amdgcn_readlane(myId, c >= 5 ? c - 5 : 0);
              A2 = sA[sp]; B2 = sB[sp]; }
            c -= 3;
            if (ALL_DEAD()) goto blend_done;
        }
        if (c >= 0) BLEND(A0, B0);
        if (c >= 1) BLEND(A1, B1);
        if (c >= 2) BLEND(A2, B2);
        if (ALL_DEAD()) goto blend_done;
    }
blend_done:
#undef BLEND
#undef ALL_DEAD

    {
        float invA = 1.0f / (1.0f + 1e-6f - TA);
        sortedPts[info.y + lane] = make_float4(
            dA,
            fminf(fmaxf(rA * invA, 0.0f), 1.0f),
            fminf(fmaxf(gA * invA, 0.0f), 1.0f),
            fminf(fmaxf(bA * invA, 0.0f), 1.0f));
        float invB = 1.0f / (1.0f + 1e-6f - TB);
        sortedPts[info.y + 64 + lane] = make_float4(
            dB,
            fminf(fmaxf(rB * invB, 0.0f), 1.0f),
            fminf(fmaxf(gB * invB, 0.0f), 1.0f),
            fminf(fmaxf(bB * invB, 0.0f), 1.0f));
    }
}

// KG: two-hop gather-unsort: i -> run (coalesced) -> slot (L3 gather) ->
// result (L3 gather) -> coalesced out writes.
__global__ __launch_bounds__(256) void kG(
    const int* __restrict__ idxToRun, const int* __restrict__ runToSlot,
    const float4* __restrict__ sortedPts, float* __restrict__ out, int n)
{
    float* rgb = out + n;
    int base = blockIdx.x * 2048 + threadIdx.x;
#pragma unroll
    for (int k = 0; k < 8; ++k) {
        int i = base + k * 256;
        if (i < n) {
            float4 v = sortedPts[runToSlot[idxToRun[i]]];
            out[i] = v.x;
            rgb[3 * i]     = v.y;
            rgb[3 * i + 1] = v.z;
            rgb[3 * i + 2] = v.w;
        }
    }
}

// ---- Fallback: R4 direct kernel ----
#define PTS 4
__global__ __launch_bounds__(256) void stroke_direct(
    const float* __restrict__ coords, const float* __restrict__ shape,
    const float* __restrict__ color, const float* __restrict__ alpha,
    float* __restrict__ out, int n, int ns)
{
    __shared__ float4 fA[MAXS + 1];
    __shared__ float4 fB[MAXS + 1];
    for (int s = threadIdx.x; s < ns; s += blockDim.x) {
        float4 sp = ((const float4*)shape)[s];
        fA[s + 1] = make_float4(sp.x, sp.y, sp.z, fmaf(-5.0f, sp.w, 0.5f));
        fB[s + 1] = make_float4(fmaxf(alpha[s], 0.0f) * 50.0f,
                                color[3 * s], color[3 * s + 1], color[3 * s + 2]);
    }
    __syncthreads();
    const int base = blockIdx.x * (blockDim.x * PTS) + threadIdx.x;
    float cx[PTS], cy[PTS], cz[PTS], T[PTS], Ad[PTS], Ar[PTS], Ag[PTS], Ab[PTS];
#pragma unroll
    for (int k = 0; k < PTS; ++k) {
        int i = base + k * 256; i = (i < n) ? i : (n - 1);
        contract_pt(coords[3 * i], coords[3 * i + 1], coords[3 * i + 2],
                    cx[k], cy[k], cz[k]);
        T[k] = 1.0f; Ad[k] = Ar[k] = Ag[k] = Ab[k] = 0.0f;
    }
    float4 a = fA[ns], b = fB[ns];
#pragma unroll 2
    for (int s = ns - 1; s >= 0; --s) {
        float4 an = fA[s], bn = fB[s];
#pragma unroll
        for (int k = 0; k < PTS; ++k) {
            float dx = cx[k] - a.x, dy = cy[k] - a.y, dz = cz[k] - a.z;
            float d2 = fmaf(dx, dx, fmaf(dy, dy, dz * dz));
            float dist = __builtin_amdgcn_sqrtf(d2);
            float omt = fminf(fmaxf(fmaf(5.0f, dist, a.w), 0.0f), 1.0f);
            float Tn = omt * T[k];
            float tT = T[k] - Tn;
            Ad[k] = fmaf(tT, b.x, Ad[k]); Ar[k] = fmaf(tT, b.y, Ar[k]);
            Ag[k] = fmaf(tT, b.z, Ag[k]); Ab[k] = fmaf(tT, b.w, Ab[k]);
            T[k] = Tn;
        }
        a = an; b = bn;
    }
    float* rgb = out + n;
    float* cw  = out + 4 * (size_t)n;
#pragma unroll
    for (int k = 0; k < PTS; ++k) {
        int i = base + k * 256;
        if (i >= n) break;
        float inv = 1.0f / (1.0f + 1e-6f - T[k]);
        out[i] = Ad[k];
        rgb[3 * i]     = fminf(fmaxf(Ar[k] * inv, 0.0f), 1.0f);
        rgb[3 * i + 1] = fminf(fmaxf(Ag[k] * inv, 0.0f), 1.0f);
        rgb[3 * i + 2] = fminf(fmaxf(Ab[k] * inv, 0.0f), 1.0f);
        cw[3 * i]     = cx[k];
        cw[3 * i + 1] = cy[k];
        cw[3 * i + 2] = cz[k];
    }
}

extern "C" void kernel_launch(void* const* d_in, const int* in_sizes, int n_in,
                              void* d_out, int out_size, void* d_ws, size_t ws_size,
                              hipStream_t stream) {
    const float* coords = (const float*)d_in[0];
    const float* shape  = (const float*)d_in[1];
    const float* color  = (const float*)d_in[2];
    const float* alpha  = (const float*)d_in[3];
    float* out = (float*)d_out;

    int n  = in_sizes[0] / 3;
    int ns = in_sizes[1] / 4;

    auto al = [](size_t v) { return (v + 255) & ~(size_t)255; };

    int nbA = (n + 2047) / 2048;
    int maxChunks = (n + CHK - 1) / CHK + 64 * 65;
    size_t slotCap = (size_t)n + 64 * 64 * CHK;

    size_t o_superCntR  = 0;                        // 2048
    size_t o_superCnt   = 2048;                     // 256
    size_t o_superBase  = 2304;                     // 256
    size_t o_superCur   = 2560;                     // 256
    size_t o_superSlotB = 2816;                     // 256
    size_t o_superChB   = 3072;                     // 256
    size_t o_segHist    = al(3328);                 // 64*NSEG*64*4 = 256KB
    size_t o_segCur     = o_segHist + 64 * NSEG * 64 * 4;   // 256KB
    size_t o_chunk      = al(o_segCur + 64 * NSEG * 64 * 4);
    size_t o_key        = al(o_chunk + (size_t)maxChunks * 8);   // n
    size_t o_i2r        = al(o_key + (size_t)n);                 // n*4
    size_t o_r2s        = al(o_i2r + (size_t)n * 4);             // n*4
    size_t o_pts        = al(o_r2s + (size_t)n * 4);             // slotCap*16
    size_t need         = o_pts + slotCap * 16;

    if (ws_size >= need && ns <= MAXS && n >= 1 && n <= (1 << 21)) {
        char* w = (char*)d_ws;
        int*    superCntR = (int*)(w + o_superCntR);
        int*    superCnt  = (int*)(w + o_superCnt);
        int*    superBase = (int*)(w + o_superBase);
        int*    superCur  = (int*)(w + o_superCur);
        int*    superSlotB= (int*)(w + o_superSlotB);
        int*    superChB  = (int*)(w + o_superChB);
        int*    segHist   = (int*)(w + o_segHist);
        int*    cellSegCur= (int*)(w + o_segCur);
        int2*   chunkInfo = (int2*)(w + o_chunk);
        u8*     keyArr    = (u8*)(w + o_key);
        int*    idxToRun  = (int*)(w + o_i2r);
        int*    runToSlot = (int*)(w + o_r2s);
        float4* sortedPts = (float4*)(w + o_pts);
        float4* sortedTmp = (float4*)out;           // aliases density+rgb

        hipMemsetAsync(superCntR, 0, 2048, stream);

        kA<<<nbA, 256, 0, stream>>>(coords, out, superCntR, n);
        kB<<<1, 64, 0, stream>>>(superCntR, superCnt, superBase, superCur,
                                 superSlotB, superChB);
        kC<<<nbA, 256, 0, stream>>>(out, superCur, sortedTmp, keyArr,
                                    idxToRun, n);
        kH<<<64 * NSEG, 256, 0, stream>>>(superCnt, superBase, keyArr, segHist);
        kB2<<<64, 64, 0, stream>>>(superCnt, superSlotB, superChB, segHist,
                                   cellSegCur, chunkInfo, maxChunks);
        kD<<<64 * NSEG, 256, 0, stream>>>(superCnt, superBase, cellSegCur,
                                          sortedTmp, sortedPts, runToSlot);
        kF<<<(maxChunks + 3) / 4, 256, 0, stream>>>(
            shape, color, alpha, chunkInfo, sortedPts, ns, maxChunks);
        kG<<<nbA, 256, 0, stream>>>(idxToRun, runToSlot, sortedPts, out, n);
    } else {
        int per_block = 256 * PTS;
        int grid = (n + per_block - 1) / per_block;
        stroke_direct<<<grid, 256, 0, stream>>>(coords, shape, color, alpha, out, n, ns);
    }
}

// Round 8
// 130.284 us; speedup vs baseline: 2.0070x; 1.8423x over previous
//
#include <hip/hip_runtime.h>

// StrokeField R14: DELETE THE SORT. Per-lane cell-list walk replaces the
// entire sort/unsort pipeline.
// R13 post-mortem: kG's 16B random gather fetches one 64B line per point
// (134MB, 46us) -- line-granularity floor; permutation costs ~45us either
// direction (gather-read or scatter-write). Meanwhile ~195us of the 240
// total is spent moving points so kF can do wave-UNIFORM stroke broadcast.
// R14 questions the premise: kE builds per-cell u16 stroke lists (4MB,
// L2-resident) once (~4us); kM processes points in ORIGINAL order -- each
// lane contracts its point, walks its own cell's list per-lane (u16 L2
// gather + 2 LDS gathers/stroke, ids independent of the T-chain so
// unroll-4 pipelines the loads), T==0 per-lane break (exact). All I/O
// coalesced: coords in, density/rgb/cw out. No sort, no unsort, no
// memsets, 2 dispatches. Cost: iterations = wave-max over 64 divergent
// lanes (~2-3x coherent) -- traded against ~195us of pipeline.

#define NC_DIM 16
#define NC (NC_DIM * NC_DIM * NC_DIM)
#define MAXS 512
#define CELL_INV 8.0f

typedef unsigned short u16;
typedef unsigned long long u64;

__device__ __forceinline__ void contract_pt(float x, float y, float z,
                                            float& cx, float& cy, float& cz) {
    float n2 = fmaf(x, x, fmaf(y, y, z * z));
    float nn = fmaxf(__builtin_amdgcn_sqrtf(n2), 1e-9f);
    float invn = 1.0f / nn;
    float scl = (nn <= 1.0f) ? 0.5f : (2.0f - invn) * (0.5f * invn);
    cx = x * scl; cy = y * scl; cz = z * scl;
}

__device__ __forceinline__ int cid_of(float cx, float cy, float cz) {
    int ix = (int)floorf((cx + 1.0f) * CELL_INV);
    int iy = (int)floorf((cy + 1.0f) * CELL_INV);
    int iz = (int)floorf((cz + 1.0f) * CELL_INV);
    ix = min(max(ix, 0), 15); iy = min(max(iy, 0), 15); iz = min(max(iz, 0), 15);
    return ix | (iy << 4) | (iz << 8);
}

// KE: per-cell ordered stroke sublist (AABB vs sphere, exact-zero margin).
// One wave per cell; ballot-compacted ascending ids. (Verified R6/R7.)
__global__ __launch_bounds__(256) void kE(
    const float* __restrict__ shape, u16* __restrict__ cellList,
    int* __restrict__ strokeCnt, int ns)
{
    int wave = (blockIdx.x * blockDim.x + threadIdx.x) >> 6;
    int lane = threadIdx.x & 63;
    if (wave >= NC) return;
    int ix = wave & 15, iy = (wave >> 4) & 15, iz = wave >> 8;
    float lox = -1.0f + ix * 0.125f, hix = lox + 0.125f;
    float loy = -1.0f + iy * 0.125f, hiy = loy + 0.125f;
    float loz = -1.0f + iz * 0.125f, hiz = loz + 0.125f;
    int cnt = 0;
    u16* lst = cellList + (size_t)wave * MAXS;
    for (int base = 0; base < ns; base += 64) {
        int s = base + lane;
        bool pass = false;
        if (s < ns) {
            float4 sp = ((const float4*)shape)[s];
            float dx = sp.x - fminf(fmaxf(sp.x, lox), hix);
            float dy = sp.y - fminf(fmaxf(sp.y, loy), hiy);
            float dz = sp.z - fminf(fmaxf(sp.z, loz), hiz);
            float d2 = fmaf(dx, dx, fmaf(dy, dy, dz * dz));
            float rr = sp.w + 0.101f;
            pass = d2 <= rr * rr;
        }
        u64 m = __ballot(pass);
        if (pass) lst[cnt + __popcll(m & ((1ull << lane) - 1ull))] = (u16)s;
        cnt += __popcll(m);
    }
    if (lane == 0) strokeCnt[wave] = cnt;
}

// KM: fused contract + per-lane cell-list blend + coalesced outputs.
// One point per thread, original order. Stroke ids are independent of the
// blend's T-chain, so the unroll-4 body issues 4 id loads + 8 LDS gathers
// together (latency amortized); T==0 group-break is exact (tT==0 after).
__global__ __launch_bounds__(256) void kM(
    const float* __restrict__ coords, const float* __restrict__ shape,
    const float* __restrict__ color, const float* __restrict__ alpha,
    const u16* __restrict__ cellList, const int* __restrict__ strokeCnt,
    float* __restrict__ out, int n, int ns)
{
    __shared__ float4 sA[MAXS];   // (ax, ay, az, K = 0.5 - 5r)
    __shared__ float4 sB[MAXS];   // (dp, cr, cg, cb)
    for (int s = threadIdx.x; s < ns; s += 256) {
        float4 sp = ((const float4*)shape)[s];
        sA[s] = make_float4(sp.x, sp.y, sp.z, fmaf(-5.0f, sp.w, 0.5f));
        sB[s] = make_float4(fmaxf(alpha[s], 0.0f) * 50.0f,
                            color[3 * s], color[3 * s + 1], color[3 * s + 2]);
    }
    __syncthreads();

    int i = blockIdx.x * 256 + threadIdx.x;
    if (i >= n) return;

    float cx, cy, cz;
    contract_pt(coords[3 * i], coords[3 * i + 1], coords[3 * i + 2], cx, cy, cz);
    float* cw = out + 4 * (size_t)n;
    cw[3 * i] = cx; cw[3 * i + 1] = cy; cw[3 * i + 2] = cz;

    int cid = cid_of(cx, cy, cz);
    int nl = strokeCnt[cid];
    const u16* lst = cellList + (size_t)cid * MAXS;

    float T = 1.0f, Ad = 0.0f, Ar = 0.0f, Ag = 0.0f, Ab = 0.0f;

#define BLEND1(AV, BV) { \
    float dx = cx - AV.x, dy = cy - AV.y, dz = cz - AV.z; \
    float d2 = fmaf(dx, dx, fmaf(dy, dy, dz * dz)); \
    float omt = __builtin_amdgcn_fmed3f( \
        fmaf(5.0f, __builtin_amdgcn_sqrtf(d2), AV.w), 0.0f, 1.0f); \
    float Tn = omt * T; float tT = T - Tn; \
    Ad = fmaf(tT, BV.x, Ad); Ar = fmaf(tT, BV.y, Ar); \
    Ag = fmaf(tT, BV.z, Ag); Ab = fmaf(tT, BV.w, Ab); T = Tn; }

    int j = nl - 1;                // descending = composite order
    while (j >= 3) {
        int i0 = lst[j], i1 = lst[j - 1], i2 = lst[j - 2], i3 = lst[j - 3];
        float4 a0 = sA[i0], b0 = sB[i0];
        float4 a1 = sA[i1], b1 = sB[i1];
        float4 a2 = sA[i2], b2 = sB[i2];
        float4 a3 = sA[i3], b3 = sB[i3];
        BLEND1(a0, b0);
        BLEND1(a1, b1);
        BLEND1(a2, b2);
        BLEND1(a3, b3);
        j -= 4;
        if (T == 0.0f) { j = -1; break; }
    }
    while (j >= 0) {
        int id = lst[j];
        float4 a = sA[id], b = sB[id];
        BLEND1(a, b);
        --j;
        if (T == 0.0f) break;
    }
#undef BLEND1

    float inv = 1.0f / (1.0f + 1e-6f - T);
    out[i] = Ad;
    float* rgb = out + n;
    rgb[3 * i]     = fminf(fmaxf(Ar * inv, 0.0f), 1.0f);
    rgb[3 * i + 1] = fminf(fmaxf(Ag * inv, 0.0f), 1.0f);
    rgb[3 * i + 2] = fminf(fmaxf(Ab * inv, 0.0f), 1.0f);
}

// ---- Fallback: R4 direct kernel ----
#define PTS 4
__global__ __launch_bounds__(256) void stroke_direct(
    const float* __restrict__ coords, const float* __restrict__ shape,
    const float* __restrict__ color, const float* __restrict__ alpha,
    float* __restrict__ out, int n, int ns)
{
    __shared__ float4 fA[MAXS + 1];
    __shared__ float4 fB[MAXS + 1];
    for (int s = threadIdx.x; s < ns; s += blockDim.x) {
        float4 sp = ((const float4*)shape)[s];
        fA[s + 1] = make_float4(sp.x, sp.y, sp.z, fmaf(-5.0f, sp.w, 0.5f));
        fB[s + 1] = make_float4(fmaxf(alpha[s], 0.0f) * 50.0f,
                                color[3 * s], color[3 * s + 1], color[3 * s + 2]);
    }
    __syncthreads();
    const int base = blockIdx.x * (blockDim.x * PTS) + threadIdx.x;
    float cx[PTS], cy[PTS], cz[PTS], T[PTS], Ad[PTS], Ar[PTS], Ag[PTS], Ab[PTS];
#pragma unroll
    for (int k = 0; k < PTS; ++k) {
        int i = base + k * 256; i = (i < n) ? i : (n - 1);
        contract_pt(coords[3 * i], coords[3 * i + 1], coords[3 * i + 2],
                    cx[k], cy[k], cz[k]);
        T[k] = 1.0f; Ad[k] = Ar[k] = Ag[k] = Ab[k] = 0.0f;
    }
    float4 a = fA[ns], b = fB[ns];
#pragma unroll 2
    for (int s = ns - 1; s >= 0; --s) {
        float4 an = fA[s], bn = fB[s];
#pragma unroll
        for (int k = 0; k < PTS; ++k) {
            float dx = cx[k] - a.x, dy = cy[k] - a.y, dz = cz[k] - a.z;
            float d2 = fmaf(dx, dx, fmaf(dy, dy, dz * dz));
            float dist = __builtin_amdgcn_sqrtf(d2);
            float omt = fminf(fmaxf(fmaf(5.0f, dist, a.w), 0.0f), 1.0f);
            float Tn = omt * T[k];
            float tT = T[k] - Tn;
            Ad[k] = fmaf(tT, b.x, Ad[k]); Ar[k] = fmaf(tT, b.y, Ar[k]);
            Ag[k] = fmaf(tT, b.z, Ag[k]); Ab[k] = fmaf(tT, b.w, Ab[k]);
            T[k] = Tn;
        }
        a = an; b = bn;
    }
    float* rgb = out + n;
    float* cw  = out + 4 * (size_t)n;
#pragma unroll
    for (int k = 0; k < PTS; ++k) {
        int i = base + k * 256;
        if (i >= n) break;
        float inv = 1.0f / (1.0f + 1e-6f - T[k]);
        out[i] = Ad[k];
        rgb[3 * i]     = fminf(fmaxf(Ar[k] * inv, 0.0f), 1.0f);
        rgb[3 * i + 1] = fminf(fmaxf(Ag[k] * inv, 0.0f), 1.0f);
        rgb[3 * i + 2] = fminf(fmaxf(Ab[k] * inv, 0.0f), 1.0f);
        cw[3 * i]     = cx[k];
        cw[3 * i + 1] = cy[k];
        cw[3 * i + 2] = cz[k];
    }
}

extern "C" void kernel_launch(void* const* d_in, const int* in_sizes, int n_in,
                              void* d_out, int out_size, void* d_ws, size_t ws_size,
                              hipStream_t stream) {
    const float* coords = (const float*)d_in[0];
    const float* shape  = (const float*)d_in[1];
    const float* color  = (const float*)d_in[2];
    const float* alpha  = (const float*)d_in[3];
    float* out = (float*)d_out;

    int n  = in_sizes[0] / 3;
    int ns = in_sizes[1] / 4;

    size_t o_list = 0;                                   // NC*MAXS*2 = 4MB
    size_t o_cnt  = (size_t)NC * MAXS * 2;               // NC*4
    size_t need   = o_cnt + (size_t)NC * 4;

    if (ws_size >= need && ns <= MAXS && n >= 1) {
        char* w = (char*)d_ws;
        u16* cellList  = (u16*)(w + o_list);
        int* strokeCnt = (int*)(w + o_cnt);

        kE<<<(NC * 64) / 256, 256, 0, stream>>>(shape, cellList, strokeCnt, ns);
        kM<<<(n + 255) / 256, 256, 0, stream>>>(coords, shape, color, alpha,
                                                cellList, strokeCnt, out, n, ns);
    } else {
        int per_block = 256 * PTS;
        int grid = (n + per_block - 1) / per_block;
        stroke_direct<<<grid, 256, 0, stream>>>(coords, shape, color, alpha, out, n, ns);
    }
}